// Round 1
// baseline (1442.000 us; speedup 1.0000x reference)
//
#include <hip/hip_runtime.h>

#define N_NODES 100000
#define N_EDGES 1600000
#define IN_F 256
#define HID 128
#define OUT_F 48
#define PAD_F 64
#define ALPHA 0.01f
#define K_STEPS 10
#define DROP_SCALE (1.0f / (1.0f + 1e-5f))

#define NT 16  // nodes per MLP block

// ---------------- MLP: h0[n][0:48] = relu(x@W1+b1)@W2+b2, pad [48:64]=0 ----
__global__ __launch_bounds__(256) void mlp_kernel(
    const float* __restrict__ x, const float* __restrict__ W1,
    const float* __restrict__ b1, const float* __restrict__ W2,
    const float* __restrict__ b2, float* __restrict__ h0) {
  __shared__ float xs[NT][IN_F];      // 16 KB
  __shared__ float w2s[HID][OUT_F];   // 24 KB
  __shared__ float h1s[NT][HID];      // 8 KB
  const int tid = threadIdx.x;
  const int n0 = blockIdx.x * NT;

  // stage W2
  for (int i = tid; i < HID * OUT_F; i += 256)
    w2s[i / OUT_F][i % OUT_F] = W2[i];
  // stage x tile (float4)
  const float4* x4 = (const float4*)(x + (size_t)n0 * IN_F);
  float4* xs4 = (float4*)&xs[0][0];
  for (int i = tid; i < NT * IN_F / 4; i += 256) xs4[i] = x4[i];
  __syncthreads();

  // layer 1: thread (j = tid&127) computes 8 nodes for its hidden unit j
  const int j = tid & 127;
  const int g = tid >> 7;  // 0..1 -> nodes g*8 .. g*8+7
  float acc[8];
#pragma unroll
  for (int i = 0; i < 8; i++) acc[i] = 0.f;
  for (int k = 0; k < IN_F; k++) {
    float w = W1[k * HID + j];
#pragma unroll
    for (int i = 0; i < 8; i++) acc[i] += xs[g * 8 + i][k] * w;
  }
  float bb = b1[j];
#pragma unroll
  for (int i = 0; i < 8; i++) h1s[g * 8 + i][j] = fmaxf(acc[i] + bb, 0.f);
  __syncthreads();

  // layer 2: NT*OUT_F = 768 outputs, 3 per thread
#pragma unroll
  for (int r = 0; r < 3; r++) {
    int idx = tid + 256 * r;
    int n = idx / OUT_F, f = idx % OUT_F;
    float a = b2[f];
    for (int k = 0; k < HID; k++) a += h1s[n][k] * w2s[k][f];
    h0[(size_t)(n0 + n) * PAD_F + f] = a;
  }
  // zero pad lanes (NT*16 = 256 -> one per thread)
  {
    int n = tid >> 4, f = OUT_F + (tid & 15);
    h0[(size_t)(n0 + n) * PAD_F + f] = 0.f;
  }
}

// ---------------- CSR build -------------------------------------------------
__global__ __launch_bounds__(256) void hist_kernel(const int* __restrict__ rows,
                                                   int* __restrict__ count) {
  int e = blockIdx.x * 256 + threadIdx.x;
  if (e < N_EDGES) atomicAdd(&count[rows[e]], 1);
}

// exclusive scan, 256 elems/block; writes per-block exclusive into partial,
// block totals into bsum
__global__ __launch_bounds__(256) void scan1_kernel(const int* __restrict__ count,
                                                    int* __restrict__ partial,
                                                    int* __restrict__ bsum) {
  __shared__ int s[256];
  int t = threadIdx.x;
  int i = blockIdx.x * 256 + t;
  int v = (i < N_NODES) ? count[i] : 0;
  s[t] = v;
  __syncthreads();
  for (int off = 1; off < 256; off <<= 1) {
    int add = (t >= off) ? s[t - off] : 0;
    __syncthreads();
    s[t] += add;
    __syncthreads();
  }
  partial[i] = s[t] - v;  // exclusive
  if (t == 255) bsum[blockIdx.x] = s[255];
}

#define NB_SCAN 391  // ceil(100000/256)
__global__ __launch_bounds__(512) void scan2_kernel(int* __restrict__ bsum) {
  __shared__ int s[512];
  int t = threadIdx.x;
  int v = (t < NB_SCAN) ? bsum[t] : 0;
  s[t] = v;
  __syncthreads();
  for (int off = 1; off < 512; off <<= 1) {
    int add = (t >= off) ? s[t - off] : 0;
    __syncthreads();
    s[t] += add;
    __syncthreads();
  }
  if (t < NB_SCAN) bsum[t] = s[t] - v;  // exclusive
}

__global__ __launch_bounds__(256) void scan3_kernel(const int* __restrict__ partial,
                                                    const int* __restrict__ bsum,
                                                    int* __restrict__ rowptr,
                                                    int* __restrict__ cursor) {
  int i = blockIdx.x * 256 + threadIdx.x;
  if (i < N_NODES) {
    int p = partial[i] + bsum[blockIdx.x];
    rowptr[i] = p;
    cursor[i] = p;
  }
  if (i == 0) rowptr[N_NODES] = N_EDGES;
}

__global__ __launch_bounds__(256) void scatter_kernel(
    const int* __restrict__ rows, const int* __restrict__ cols,
    const float* __restrict__ vals, int* __restrict__ cursor,
    int* __restrict__ ccol, float* __restrict__ cval) {
  int e = blockIdx.x * 256 + threadIdx.x;
  if (e < N_EDGES) {
    int r = rows[e];
    int p = atomicAdd(&cursor[r], 1);
    ccol[p] = cols[e];
    cval[p] = vals[e] * (DROP_SCALE * (1.0f - ALPHA));
  }
}

// ---------------- propagation: one wave per row, lane = feature ------------
__global__ __launch_bounds__(256) void prop_kernel(
    const float* __restrict__ hin, float* __restrict__ hout,
    const int* __restrict__ rowptr, const int* __restrict__ ccol,
    const float* __restrict__ cval) {
  int r = (blockIdx.x * 256 + threadIdx.x) >> 6;  // global wave id = row
  int lane = threadIdx.x & 63;
  if (r >= N_NODES) return;
  int s = rowptr[r];
  int e = rowptr[r + 1];
  s = __builtin_amdgcn_readfirstlane(s);
  e = __builtin_amdgcn_readfirstlane(e);
  float acc = ALPHA * hin[(size_t)r * PAD_F + lane];
  for (int i = s; i < e; i++) {
    int c = ccol[i];
    float v = cval[i];
    acc += v * hin[(size_t)c * PAD_F + lane];
  }
  hout[(size_t)r * PAD_F + lane] = acc;
}

__global__ __launch_bounds__(256) void pack_kernel(const float* __restrict__ hin,
                                                   float* __restrict__ out) {
  int i = blockIdx.x * 256 + threadIdx.x;
  if (i < N_NODES * OUT_F) {
    int n = i / OUT_F, f = i - n * OUT_F;
    out[i] = hin[(size_t)n * PAD_F + f];
  }
}

// ---------------- launch ----------------------------------------------------
extern "C" void kernel_launch(void* const* d_in, const int* in_sizes, int n_in,
                              void* d_out, int out_size, void* d_ws,
                              size_t ws_size, hipStream_t stream) {
  const float* x = (const float*)d_in[0];
  const int* rows = (const int*)d_in[1];
  const int* cols = (const int*)d_in[2];
  const float* vals = (const float*)d_in[3];
  const float* W1 = (const float*)d_in[4];
  const float* b1 = (const float*)d_in[5];
  const float* W2 = (const float*)d_in[6];
  const float* b2 = (const float*)d_in[7];
  float* out = (float*)d_out;

  char* ws = (char*)d_ws;
  const size_t HA_OFF = 0;                       // 25,600,000
  const size_t HB_OFF = 25600000;                // 25,600,000
  const size_t CVAL_OFF = 51200000;              // 6,400,000
  const size_t CCOL_OFF = 57600000;              // 6,400,000
  const size_t ROWPTR_OFF = 64000000;            // 400,128
  const size_t CURSOR_OFF = 64400128;            // 400,128
  const size_t COUNT_OFF = 64800256;             // 400,128
  const size_t PARTIAL_OFF = 65200384;           // 400,384 (391*256*4)
  const size_t BSUM_OFF = 65600768;              // 2,048

  float* hA = (float*)(ws + HA_OFF);
  float* hB = (float*)(ws + HB_OFF);
  float* cval = (float*)(ws + CVAL_OFF);
  int* ccol = (int*)(ws + CCOL_OFF);
  int* rowptr = (int*)(ws + ROWPTR_OFF);
  int* cursor = (int*)(ws + CURSOR_OFF);
  int* count = (int*)(ws + COUNT_OFF);
  int* partial = (int*)(ws + PARTIAL_OFF);
  int* bsum = (int*)(ws + BSUM_OFF);

  // MLP -> hA (padded [N][64])
  mlp_kernel<<<N_NODES / NT, 256, 0, stream>>>(x, W1, b1, W2, b2, hA);

  // CSR build
  hipMemsetAsync(count, 0, N_NODES * sizeof(int), stream);
  hist_kernel<<<(N_EDGES + 255) / 256, 256, 0, stream>>>(rows, count);
  scan1_kernel<<<NB_SCAN, 256, 0, stream>>>(count, partial, bsum);
  scan2_kernel<<<1, 512, 0, stream>>>(bsum);
  scan3_kernel<<<NB_SCAN, 256, 0, stream>>>(partial, bsum, rowptr, cursor);
  scatter_kernel<<<(N_EDGES + 255) / 256, 256, 0, stream>>>(rows, cols, vals,
                                                            cursor, ccol, cval);

  // K propagation steps, ping-pong hA <-> hB (K even -> final in hA)
  const int PROP_BLOCKS = (N_NODES * 64 + 255) / 256;
  for (int k = 0; k < K_STEPS; k++) {
    const float* hin = (k & 1) ? hB : hA;
    float* hout = (k & 1) ? hA : hB;
    prop_kernel<<<PROP_BLOCKS, 256, 0, stream>>>(hin, hout, rowptr, ccol, cval);
  }

  // pack [N][64] -> [N][48]
  pack_kernel<<<(N_NODES * OUT_F + 255) / 256, 256, 0, stream>>>(hA, out);
}

// Round 2
// 961.689 us; speedup vs baseline: 1.4994x; 1.4994x over previous
//
#include <hip/hip_runtime.h>

#define N_NODES 100000
#define N_EDGES 1600000
#define IN_F 256
#define HID 128
#define OUT_F 48
#define ALPHA 0.01f
#define K_STEPS 10
#define DROP_SCALE (1.0f / (1.0f + 1e-5f))

typedef __bf16 v8bf __attribute__((ext_vector_type(8)));
typedef float v4f __attribute__((ext_vector_type(4)));

static __device__ __forceinline__ __bf16 tobf(float f) { return (__bf16)f; }

// ---------------- weight transpose+convert: W1[256][128]->w1t[128][256] bf16,
//                  W2[128][48]->w2t[48][128] bf16 --------------------------
__global__ __launch_bounds__(256) void conv_w(const float* __restrict__ W1,
                                              const float* __restrict__ W2,
                                              __bf16* __restrict__ w1t,
                                              __bf16* __restrict__ w2t) {
  int i = blockIdx.x * 256 + threadIdx.x;
  if (i < HID * IN_F) {
    int n = i >> 8, k = i & 255;
    w1t[i] = tobf(W1[k * HID + n]);
  }
  int j = i - HID * IN_F;
  if (j >= 0 && j < OUT_F * HID) {
    int n = j >> 7, k = j & 127;
    w2t[j] = tobf(W2[k * OUT_F + n]);
  }
}

// ---------------- fused MLP via MFMA: h0 = (relu(x@W1+b1))@W2+b2 (bf16 out) -
#define BM 64
__global__ __launch_bounds__(256) void mlp_mfma(
    const float* __restrict__ x, const __bf16* __restrict__ w1t,
    const float* __restrict__ b1, const __bf16* __restrict__ w2t,
    const float* __restrict__ b2, __bf16* __restrict__ h0) {
  __shared__ __bf16 xs[BM][264];    // 256 + 8 pad
  __shared__ __bf16 h1s[BM][136];   // 128 + 8 pad
  __shared__ __bf16 w2s[OUT_F][136];
  __shared__ float b1s[HID];
  __shared__ float b2s[OUT_F];

  const int tid = threadIdx.x;
  const int n0 = blockIdx.x * BM;

  // stage x tile (fp32 -> bf16), guarded for the ragged last block
  for (int i = tid; i < BM * 64; i += 256) {
    int r = i >> 6, c4 = i & 63;
    int gr = n0 + r;
    float4 v = make_float4(0.f, 0.f, 0.f, 0.f);
    if (gr < N_NODES) v = ((const float4*)(x + (size_t)gr * IN_F))[c4];
    __bf16* d = &xs[r][c4 * 4];
    d[0] = tobf(v.x); d[1] = tobf(v.y); d[2] = tobf(v.z); d[3] = tobf(v.w);
  }
  // stage w2t, biases
  for (int i = tid; i < OUT_F * HID; i += 256) w2s[i >> 7][i & 127] = w2t[i];
  if (tid < HID) b1s[tid] = b1[tid];
  if (tid < OUT_F) b2s[tid] = b2[tid];
  __syncthreads();

  const int wv = tid >> 6;
  const int l = tid & 63;
  const int lm = l & 15;
  const int ko = (l >> 4) * 8;
  const int row = (wv << 4) + lm;  // local A row for this lane

  // ---- layer 1: [16x256] @ [256x128] per wave -> acc1[8] frags ----
  v4f acc1[8];
#pragma unroll
  for (int nf = 0; nf < 8; nf++) acc1[nf] = (v4f){0.f, 0.f, 0.f, 0.f};

  const __bf16* w1base = w1t + (size_t)lm * IN_F + ko;
#pragma unroll
  for (int k0 = 0; k0 < 8; k0++) {
    v8bf a = *(const v8bf*)&xs[row][k0 * 32 + ko];
#pragma unroll
    for (int nf = 0; nf < 8; nf++) {
      v8bf b = *(const v8bf*)(w1base + nf * 16 * IN_F + k0 * 32);
      acc1[nf] = __builtin_amdgcn_mfma_f32_16x16x32_bf16(a, b, acc1[nf], 0, 0, 0);
    }
  }
  // epilogue: bias + relu -> h1s (bf16). D: row=(l>>4)*4+q, col=lm
#pragma unroll
  for (int nf = 0; nf < 8; nf++) {
    float bb = b1s[nf * 16 + lm];
#pragma unroll
    for (int q = 0; q < 4; q++) {
      int rr = (wv << 4) + (l >> 4) * 4 + q;
      h1s[rr][nf * 16 + lm] = tobf(fmaxf(acc1[nf][q] + bb, 0.f));
    }
  }
  __syncthreads();

  // ---- layer 2: [16x128] @ [128x48] per wave ----
  v4f acc2[3];
#pragma unroll
  for (int nf = 0; nf < 3; nf++) acc2[nf] = (v4f){0.f, 0.f, 0.f, 0.f};
#pragma unroll
  for (int k0 = 0; k0 < 4; k0++) {
    v8bf a = *(const v8bf*)&h1s[row][k0 * 32 + ko];
#pragma unroll
    for (int nf = 0; nf < 3; nf++) {
      v8bf b = *(const v8bf*)&w2s[nf * 16 + lm][k0 * 32 + ko];
      acc2[nf] = __builtin_amdgcn_mfma_f32_16x16x32_bf16(a, b, acc2[nf], 0, 0, 0);
    }
  }
#pragma unroll
  for (int nf = 0; nf < 3; nf++) {
    float bb = b2s[nf * 16 + lm];
#pragma unroll
    for (int q = 0; q < 4; q++) {
      int node = n0 + (wv << 4) + (l >> 4) * 4 + q;
      if (node < N_NODES)
        h0[(size_t)node * OUT_F + nf * 16 + lm] = tobf(acc2[nf][q] + bb);
    }
  }
}

// ---------------- CSR build -------------------------------------------------
__global__ __launch_bounds__(256) void hist_kernel(const int* __restrict__ rows,
                                                   int* __restrict__ count) {
  int e = blockIdx.x * 256 + threadIdx.x;
  if (e < N_EDGES) atomicAdd(&count[rows[e]], 1);
}

__global__ __launch_bounds__(256) void scan1_kernel(const int* __restrict__ count,
                                                    int* __restrict__ partial,
                                                    int* __restrict__ bsum) {
  __shared__ int s[256];
  int t = threadIdx.x;
  int i = blockIdx.x * 256 + t;
  int v = (i < N_NODES) ? count[i] : 0;
  s[t] = v;
  __syncthreads();
  for (int off = 1; off < 256; off <<= 1) {
    int add = (t >= off) ? s[t - off] : 0;
    __syncthreads();
    s[t] += add;
    __syncthreads();
  }
  partial[i] = s[t] - v;
  if (t == 255) bsum[blockIdx.x] = s[255];
}

#define NB_SCAN 391
__global__ __launch_bounds__(512) void scan2_kernel(int* __restrict__ bsum) {
  __shared__ int s[512];
  int t = threadIdx.x;
  int v = (t < NB_SCAN) ? bsum[t] : 0;
  s[t] = v;
  __syncthreads();
  for (int off = 1; off < 512; off <<= 1) {
    int add = (t >= off) ? s[t - off] : 0;
    __syncthreads();
    s[t] += add;
    __syncthreads();
  }
  if (t < NB_SCAN) bsum[t] = s[t] - v;
}

__global__ __launch_bounds__(256) void scan3_kernel(const int* __restrict__ partial,
                                                    const int* __restrict__ bsum,
                                                    int* __restrict__ rowptr,
                                                    int* __restrict__ cursor) {
  int i = blockIdx.x * 256 + threadIdx.x;
  if (i < N_NODES) {
    int p = partial[i] + bsum[blockIdx.x];
    rowptr[i] = p;
    cursor[i] = p;
  }
  if (i == 0) rowptr[N_NODES] = N_EDGES;
}

__global__ __launch_bounds__(256) void scatter_kernel(
    const int* __restrict__ rows, const int* __restrict__ cols,
    const float* __restrict__ vals, int* __restrict__ cursor,
    int* __restrict__ ccol, float* __restrict__ cval) {
  int e = blockIdx.x * 256 + threadIdx.x;
  if (e < N_EDGES) {
    int r = rows[e];
    int p = atomicAdd(&cursor[r], 1);
    ccol[p] = cols[e];
    cval[p] = vals[e] * (DROP_SCALE * (1.0f - ALPHA));
  }
}

// ---------------- propagation: wave per row, lane = feature (48 active) ----
template <int FINAL>
__global__ __launch_bounds__(256) void prop_kernel(
    const __bf16* __restrict__ hin, __bf16* __restrict__ hout,
    float* __restrict__ fout, const int* __restrict__ rowptr,
    const int* __restrict__ ccol, const float* __restrict__ cval) {
  int wid = (blockIdx.x * 256 + threadIdx.x) >> 6;
  int lane = threadIdx.x & 63;
  if (wid >= N_NODES) return;
  int s = __builtin_amdgcn_readfirstlane(rowptr[wid]);
  int e = __builtin_amdgcn_readfirstlane(rowptr[wid + 1]);
  const bool act = lane < OUT_F;
  const size_t self = (size_t)wid * OUT_F + lane;
  float acc = 0.f;
  if (act) acc = ALPHA * (float)hin[self];
  int i = s;
  for (; i + 1 < e; i += 2) {
    int c0 = ccol[i], c1 = ccol[i + 1];
    float v0 = cval[i], v1 = cval[i + 1];
    if (act) {
      float g0 = (float)hin[(size_t)c0 * OUT_F + lane];
      float g1 = (float)hin[(size_t)c1 * OUT_F + lane];
      acc += v0 * g0;
      acc += v1 * g1;
    }
  }
  if (i < e) {
    int c = ccol[i];
    float v = cval[i];
    if (act) acc += v * (float)hin[(size_t)c * OUT_F + lane];
  }
  if (act) {
    if (FINAL)
      fout[self] = acc;
    else
      hout[self] = tobf(acc);
  }
}

// ---------------- launch ----------------------------------------------------
extern "C" void kernel_launch(void* const* d_in, const int* in_sizes, int n_in,
                              void* d_out, int out_size, void* d_ws,
                              size_t ws_size, hipStream_t stream) {
  const float* x = (const float*)d_in[0];
  const int* rows = (const int*)d_in[1];
  const int* cols = (const int*)d_in[2];
  const float* vals = (const float*)d_in[3];
  const float* W1 = (const float*)d_in[4];
  const float* b1 = (const float*)d_in[5];
  const float* W2 = (const float*)d_in[6];
  const float* b2 = (const float*)d_in[7];
  float* out = (float*)d_out;

  char* ws = (char*)d_ws;
  const size_t HA_OFF = 0;                 // 9,600,000 (bf16 h ping)
  const size_t HB_OFF = 9600000;           // 9,600,000 (bf16 h pong)
  const size_t CVAL_OFF = 19200000;        // 6,400,000
  const size_t CCOL_OFF = 25600000;        // 6,400,000
  const size_t ROWPTR_OFF = 32000000;      // 400,128
  const size_t CURSOR_OFF = 32400128;      // 400,128
  const size_t COUNT_OFF = 32800256;       // 400,128
  const size_t PARTIAL_OFF = 33200384;     // 400,384
  const size_t BSUM_OFF = 33600768;        // 2,048
  const size_t W1T_OFF = 33602816;         // 65,536
  const size_t W2T_OFF = 33668352;         // 12,288

  __bf16* hA = (__bf16*)(ws + HA_OFF);
  __bf16* hB = (__bf16*)(ws + HB_OFF);
  float* cval = (float*)(ws + CVAL_OFF);
  int* ccol = (int*)(ws + CCOL_OFF);
  int* rowptr = (int*)(ws + ROWPTR_OFF);
  int* cursor = (int*)(ws + CURSOR_OFF);
  int* count = (int*)(ws + COUNT_OFF);
  int* partial = (int*)(ws + PARTIAL_OFF);
  int* bsum = (int*)(ws + BSUM_OFF);
  __bf16* w1t = (__bf16*)(ws + W1T_OFF);
  __bf16* w2t = (__bf16*)(ws + W2T_OFF);

  // weights convert/transpose, then fused MFMA MLP -> hA (bf16 [N][48])
  conv_w<<<(HID * IN_F + OUT_F * HID + 255) / 256, 256, 0, stream>>>(W1, W2, w1t, w2t);
  mlp_mfma<<<(N_NODES + BM - 1) / BM, 256, 0, stream>>>(x, w1t, b1, w2t, b2, hA);

  // CSR build
  hipMemsetAsync(count, 0, N_NODES * sizeof(int), stream);
  hist_kernel<<<(N_EDGES + 255) / 256, 256, 0, stream>>>(rows, count);
  scan1_kernel<<<NB_SCAN, 256, 0, stream>>>(count, partial, bsum);
  scan2_kernel<<<1, 512, 0, stream>>>(bsum);
  scan3_kernel<<<NB_SCAN, 256, 0, stream>>>(partial, bsum, rowptr, cursor);
  scatter_kernel<<<(N_EDGES + 255) / 256, 256, 0, stream>>>(rows, cols, vals,
                                                            cursor, ccol, cval);

  // K propagation steps, ping-pong; final step writes fp32 directly to out
  const int PROP_BLOCKS = (N_NODES * 64 + 255) / 256;
  for (int k = 0; k < K_STEPS - 1; k++) {
    const __bf16* hin = (k & 1) ? hB : hA;
    __bf16* hout = (k & 1) ? hA : hB;
    prop_kernel<0><<<PROP_BLOCKS, 256, 0, stream>>>(hin, hout, nullptr, rowptr,
                                                    ccol, cval);
  }
  prop_kernel<1><<<PROP_BLOCKS, 256, 0, stream>>>(hB, nullptr, out, rowptr,
                                                  ccol, cval);
}

// Round 3
// 767.328 us; speedup vs baseline: 1.8792x; 1.2533x over previous
//
#include <hip/hip_runtime.h>

#define N_NODES 100000
#define N_EDGES 1600000
#define IN_F 256
#define HID 128
#define OUT_F 48
#define PAD_F 64
#define ALPHA 0.01f
#define K_STEPS 10
#define DROP_SCALE (1.0f / (1.0f + 1e-5f))

typedef __bf16 v8bf __attribute__((ext_vector_type(8)));
typedef float v4f __attribute__((ext_vector_type(4)));
typedef unsigned long long u64;

static __device__ __forceinline__ __bf16 tobf(float f) { return (__bf16)f; }

// ---------------- weight transpose+convert ---------------------------------
__global__ __launch_bounds__(256) void conv_w(const float* __restrict__ W1,
                                              const float* __restrict__ W2,
                                              __bf16* __restrict__ w1t,
                                              __bf16* __restrict__ w2t) {
  int i = blockIdx.x * 256 + threadIdx.x;
  if (i < HID * IN_F) {
    int n = i >> 8, k = i & 255;
    w1t[i] = tobf(W1[k * HID + n]);
  }
  int j = i - HID * IN_F;
  if (j >= 0 && j < OUT_F * HID) {
    int n = j >> 7, k = j & 127;
    w2t[j] = tobf(W2[k * OUT_F + n]);
  }
}

// ---------------- fused MLP via MFMA -> h0 bf16 [N][64] (cols 48-63 = 0) ---
#define BM 64
__global__ __launch_bounds__(256) void mlp_mfma(
    const float* __restrict__ x, const __bf16* __restrict__ w1t,
    const float* __restrict__ b1, const __bf16* __restrict__ w2t,
    const float* __restrict__ b2, __bf16* __restrict__ h0) {
  __shared__ __bf16 xs[BM][264];
  __shared__ __bf16 h1s[BM][136];
  __shared__ __bf16 w2s[OUT_F][136];
  __shared__ float b1s[HID];
  __shared__ float b2s[OUT_F];

  const int tid = threadIdx.x;
  const int n0 = blockIdx.x * BM;

  for (int i = tid; i < BM * 64; i += 256) {
    int r = i >> 6, c4 = i & 63;
    int gr = n0 + r;
    float4 v = make_float4(0.f, 0.f, 0.f, 0.f);
    if (gr < N_NODES) v = ((const float4*)(x + (size_t)gr * IN_F))[c4];
    __bf16* d = &xs[r][c4 * 4];
    d[0] = tobf(v.x); d[1] = tobf(v.y); d[2] = tobf(v.z); d[3] = tobf(v.w);
  }
  for (int i = tid; i < OUT_F * HID; i += 256) w2s[i >> 7][i & 127] = w2t[i];
  if (tid < HID) b1s[tid] = b1[tid];
  if (tid < OUT_F) b2s[tid] = b2[tid];
  __syncthreads();

  const int wv = tid >> 6;
  const int l = tid & 63;
  const int lm = l & 15;
  const int ko = (l >> 4) * 8;
  const int row = (wv << 4) + lm;

  v4f acc1[8];
#pragma unroll
  for (int nf = 0; nf < 8; nf++) acc1[nf] = (v4f){0.f, 0.f, 0.f, 0.f};

  const __bf16* w1base = w1t + (size_t)lm * IN_F + ko;
#pragma unroll
  for (int k0 = 0; k0 < 8; k0++) {
    v8bf a = *(const v8bf*)&xs[row][k0 * 32 + ko];
#pragma unroll
    for (int nf = 0; nf < 8; nf++) {
      v8bf b = *(const v8bf*)(w1base + nf * 16 * IN_F + k0 * 32);
      acc1[nf] = __builtin_amdgcn_mfma_f32_16x16x32_bf16(a, b, acc1[nf], 0, 0, 0);
    }
  }
#pragma unroll
  for (int nf = 0; nf < 8; nf++) {
    float bb = b1s[nf * 16 + lm];
#pragma unroll
    for (int q = 0; q < 4; q++) {
      int rr = (wv << 4) + (l >> 4) * 4 + q;
      h1s[rr][nf * 16 + lm] = tobf(fmaxf(acc1[nf][q] + bb, 0.f));
    }
  }
  __syncthreads();

  v4f acc2[3];
#pragma unroll
  for (int nf = 0; nf < 3; nf++) acc2[nf] = (v4f){0.f, 0.f, 0.f, 0.f};
#pragma unroll
  for (int k0 = 0; k0 < 4; k0++) {
    v8bf a = *(const v8bf*)&h1s[row][k0 * 32 + ko];
#pragma unroll
    for (int nf = 0; nf < 3; nf++) {
      v8bf b = *(const v8bf*)&w2s[nf * 16 + lm][k0 * 32 + ko];
      acc2[nf] = __builtin_amdgcn_mfma_f32_16x16x32_bf16(a, b, acc2[nf], 0, 0, 0);
    }
  }
#pragma unroll
  for (int nf = 0; nf < 3; nf++) {
    float bb = b2s[nf * 16 + lm];
#pragma unroll
    for (int q = 0; q < 4; q++) {
      int node = n0 + (wv << 4) + (l >> 4) * 4 + q;
      if (node < N_NODES)
        h0[(size_t)node * PAD_F + nf * 16 + lm] = tobf(acc2[nf][q] + bb);
    }
  }
  // zero the pad columns 48..63
  for (int i = tid; i < BM * 16; i += 256) {
    int r = i >> 4, c = 48 + (i & 15);
    int node = n0 + r;
    if (node < N_NODES) h0[(size_t)node * PAD_F + c] = (__bf16)0.f;
  }
}

// ---------------- CSR build -------------------------------------------------
__global__ __launch_bounds__(256) void hist_kernel(const int* __restrict__ rows,
                                                   int* __restrict__ count) {
  int e = blockIdx.x * 256 + threadIdx.x;
  if (e < N_EDGES) atomicAdd(&count[rows[e]], 1);
}

__global__ __launch_bounds__(256) void scan1_kernel(const int* __restrict__ count,
                                                    int* __restrict__ partial,
                                                    int* __restrict__ bsum) {
  __shared__ int s[256];
  int t = threadIdx.x;
  int i = blockIdx.x * 256 + t;
  int v = (i < N_NODES) ? count[i] : 0;
  s[t] = v;
  __syncthreads();
  for (int off = 1; off < 256; off <<= 1) {
    int add = (t >= off) ? s[t - off] : 0;
    __syncthreads();
    s[t] += add;
    __syncthreads();
  }
  partial[i] = s[t] - v;
  if (t == 255) bsum[blockIdx.x] = s[255];
}

#define NB_SCAN 391
__global__ __launch_bounds__(512) void scan2_kernel(int* __restrict__ bsum) {
  __shared__ int s[512];
  int t = threadIdx.x;
  int v = (t < NB_SCAN) ? bsum[t] : 0;
  s[t] = v;
  __syncthreads();
  for (int off = 1; off < 512; off <<= 1) {
    int add = (t >= off) ? s[t - off] : 0;
    __syncthreads();
    s[t] += add;
    __syncthreads();
  }
  if (t < NB_SCAN) bsum[t] = s[t] - v;
}

__global__ __launch_bounds__(256) void scan3_kernel(const int* __restrict__ partial,
                                                    const int* __restrict__ bsum,
                                                    int* __restrict__ rowptr,
                                                    int* __restrict__ cursor) {
  int i = blockIdx.x * 256 + threadIdx.x;
  if (i < N_NODES) {
    int p = partial[i] + bsum[blockIdx.x];
    rowptr[i] = p;
    cursor[i] = p;
  }
  if (i == 0) rowptr[N_NODES] = N_EDGES;
}

// packed edge record: low 32 = col, high 32 = f32 bits of scaled val
__global__ __launch_bounds__(256) void scatter_kernel(
    const int* __restrict__ rows, const int* __restrict__ cols,
    const float* __restrict__ vals, int* __restrict__ cursor,
    u64* __restrict__ edges) {
  int e = blockIdx.x * 256 + threadIdx.x;
  if (e < N_EDGES) {
    int r = rows[e];
    float v = vals[e] * (DROP_SCALE * (1.0f - ALPHA));
    u64 rec = ((u64)__float_as_uint(v) << 32) | (unsigned)cols[e];
    int p = atomicAdd(&cursor[r], 1);
    edges[p] = rec;
  }
}

// ---------------- propagation: wave per row, lane = feature, 128B rows -----
template <int FINAL>
__global__ __launch_bounds__(256) void prop_kernel(
    const __bf16* __restrict__ hin, __bf16* __restrict__ hout,
    float* __restrict__ fout, const int* __restrict__ rowptr,
    const u64* __restrict__ edges) {
  int wid = (blockIdx.x * 256 + threadIdx.x) >> 6;
  int lane = threadIdx.x & 63;
  if (wid >= N_NODES) return;
  int s = __builtin_amdgcn_readfirstlane(rowptr[wid]);
  int e = __builtin_amdgcn_readfirstlane(rowptr[wid + 1]);
  float acc = ALPHA * (float)hin[(size_t)wid * PAD_F + lane];
  int i = s;
  for (; i + 3 < e; i += 4) {
    u64 q0 = edges[i], q1 = edges[i + 1], q2 = edges[i + 2], q3 = edges[i + 3];
    float g0 = (float)hin[(int)(q0 & 0xffffffffu) * PAD_F + lane];
    float g1 = (float)hin[(int)(q1 & 0xffffffffu) * PAD_F + lane];
    float g2 = (float)hin[(int)(q2 & 0xffffffffu) * PAD_F + lane];
    float g3 = (float)hin[(int)(q3 & 0xffffffffu) * PAD_F + lane];
    acc = fmaf(__uint_as_float((unsigned)(q0 >> 32)), g0, acc);
    acc = fmaf(__uint_as_float((unsigned)(q1 >> 32)), g1, acc);
    acc = fmaf(__uint_as_float((unsigned)(q2 >> 32)), g2, acc);
    acc = fmaf(__uint_as_float((unsigned)(q3 >> 32)), g3, acc);
  }
  for (; i < e; i++) {
    u64 q = edges[i];
    float g = (float)hin[(int)(q & 0xffffffffu) * PAD_F + lane];
    acc = fmaf(__uint_as_float((unsigned)(q >> 32)), g, acc);
  }
  if (FINAL) {
    if (lane < OUT_F) fout[(size_t)wid * OUT_F + lane] = acc;
  } else {
    hout[(size_t)wid * PAD_F + lane] = tobf(acc);
  }
}

// ---------------- launch ----------------------------------------------------
extern "C" void kernel_launch(void* const* d_in, const int* in_sizes, int n_in,
                              void* d_out, int out_size, void* d_ws,
                              size_t ws_size, hipStream_t stream) {
  const float* x = (const float*)d_in[0];
  const int* rows = (const int*)d_in[1];
  const int* cols = (const int*)d_in[2];
  const float* vals = (const float*)d_in[3];
  const float* W1 = (const float*)d_in[4];
  const float* b1 = (const float*)d_in[5];
  const float* W2 = (const float*)d_in[6];
  const float* b2 = (const float*)d_in[7];
  float* out = (float*)d_out;

  char* ws = (char*)d_ws;
  const size_t HA_OFF = 0;                 // 12,800,000
  const size_t HB_OFF = 12800000;          // 12,800,000
  const size_t EDGES_OFF = 25600000;       // 12,800,000
  const size_t ROWPTR_OFF = 38400000;      // 400,128
  const size_t CURSOR_OFF = 38800128;      // 400,000
  const size_t COUNT_OFF = 39200128;       // 400,000
  const size_t PARTIAL_OFF = 39600128;     // 400,384
  const size_t BSUM_OFF = 40000512;        // 2,048
  const size_t W1T_OFF = 40002560;         // 65,536
  const size_t W2T_OFF = 40068096;         // 12,288

  __bf16* hA = (__bf16*)(ws + HA_OFF);
  __bf16* hB = (__bf16*)(ws + HB_OFF);
  u64* edges = (u64*)(ws + EDGES_OFF);
  int* rowptr = (int*)(ws + ROWPTR_OFF);
  int* cursor = (int*)(ws + CURSOR_OFF);
  int* count = (int*)(ws + COUNT_OFF);
  int* partial = (int*)(ws + PARTIAL_OFF);
  int* bsum = (int*)(ws + BSUM_OFF);
  __bf16* w1t = (__bf16*)(ws + W1T_OFF);
  __bf16* w2t = (__bf16*)(ws + W2T_OFF);

  conv_w<<<(HID * IN_F + OUT_F * HID + 255) / 256, 256, 0, stream>>>(W1, W2, w1t, w2t);
  mlp_mfma<<<(N_NODES + BM - 1) / BM, 256, 0, stream>>>(x, w1t, b1, w2t, b2, hA);

  hipMemsetAsync(count, 0, N_NODES * sizeof(int), stream);
  hist_kernel<<<(N_EDGES + 255) / 256, 256, 0, stream>>>(rows, count);
  scan1_kernel<<<NB_SCAN, 256, 0, stream>>>(count, partial, bsum);
  scan2_kernel<<<1, 512, 0, stream>>>(bsum);
  scan3_kernel<<<NB_SCAN, 256, 0, stream>>>(partial, bsum, rowptr, cursor);
  scatter_kernel<<<(N_EDGES + 255) / 256, 256, 0, stream>>>(rows, cols, vals,
                                                            cursor, edges);

  const int PROP_BLOCKS = (N_NODES * 64 + 255) / 256;
  for (int k = 0; k < K_STEPS - 1; k++) {
    const __bf16* hin = (k & 1) ? hB : hA;
    __bf16* hout = (k & 1) ? hA : hB;
    prop_kernel<0><<<PROP_BLOCKS, 256, 0, stream>>>(hin, hout, nullptr, rowptr,
                                                    edges);
  }
  prop_kernel<1><<<PROP_BLOCKS, 256, 0, stream>>>(hB, nullptr, out, rowptr,
                                                  edges);
}

// Round 4
// 689.444 us; speedup vs baseline: 2.0915x; 1.1130x over previous
//
#include <hip/hip_runtime.h>

#define N_NODES 100000
#define N_EDGES 1600000
#define IN_F 256
#define HID 128
#define OUT_F 48
#define PAD_F 64
#define ALPHA 0.01f
#define K_STEPS 10
#define DROP_SCALE (1.0f / (1.0f + 1e-5f))

#define NBUCK 196      // ceil(100000 / 512) rows-per-bucket buckets
#define BCAP 10240     // bucket capacity (mean 8192, sigma ~90 -> 22 sigma)

typedef __bf16 v8bf __attribute__((ext_vector_type(8)));
typedef float v4f __attribute__((ext_vector_type(4)));
typedef unsigned long long u64;

static __device__ __forceinline__ __bf16 tobf(float f) { return (__bf16)f; }

// ---------------- weight transpose+convert ---------------------------------
__global__ __launch_bounds__(256) void conv_w(const float* __restrict__ W1,
                                              const float* __restrict__ W2,
                                              __bf16* __restrict__ w1t,
                                              __bf16* __restrict__ w2t) {
  int i = blockIdx.x * 256 + threadIdx.x;
  if (i < HID * IN_F) {
    int n = i >> 8, k = i & 255;
    w1t[i] = tobf(W1[k * HID + n]);
  }
  int j = i - HID * IN_F;
  if (j >= 0 && j < OUT_F * HID) {
    int n = j >> 7, k = j & 127;
    w2t[j] = tobf(W2[k * OUT_F + n]);
  }
}

// ---------------- fused MLP via MFMA -> h0 bf16 [N][64] (cols 48-63 = 0) ---
#define BM 64
__global__ __launch_bounds__(256) void mlp_mfma(
    const float* __restrict__ x, const __bf16* __restrict__ w1t,
    const float* __restrict__ b1, const __bf16* __restrict__ w2t,
    const float* __restrict__ b2, __bf16* __restrict__ h0) {
  __shared__ __bf16 xs[BM][264];
  __shared__ __bf16 h1s[BM][136];
  __shared__ __bf16 w2s[OUT_F][136];
  __shared__ float b1s[HID];
  __shared__ float b2s[OUT_F];

  const int tid = threadIdx.x;
  const int n0 = blockIdx.x * BM;

  for (int i = tid; i < BM * 64; i += 256) {
    int r = i >> 6, c4 = i & 63;
    int gr = n0 + r;
    float4 v = make_float4(0.f, 0.f, 0.f, 0.f);
    if (gr < N_NODES) v = ((const float4*)(x + (size_t)gr * IN_F))[c4];
    __bf16* d = &xs[r][c4 * 4];
    d[0] = tobf(v.x); d[1] = tobf(v.y); d[2] = tobf(v.z); d[3] = tobf(v.w);
  }
  for (int i = tid; i < OUT_F * HID; i += 256) w2s[i >> 7][i & 127] = w2t[i];
  if (tid < HID) b1s[tid] = b1[tid];
  if (tid < OUT_F) b2s[tid] = b2[tid];
  __syncthreads();

  const int wv = tid >> 6;
  const int l = tid & 63;
  const int lm = l & 15;
  const int ko = (l >> 4) * 8;
  const int row = (wv << 4) + lm;

  v4f acc1[8];
#pragma unroll
  for (int nf = 0; nf < 8; nf++) acc1[nf] = (v4f){0.f, 0.f, 0.f, 0.f};

  const __bf16* w1base = w1t + (size_t)lm * IN_F + ko;
#pragma unroll
  for (int k0 = 0; k0 < 8; k0++) {
    v8bf a = *(const v8bf*)&xs[row][k0 * 32 + ko];
#pragma unroll
    for (int nf = 0; nf < 8; nf++) {
      v8bf b = *(const v8bf*)(w1base + nf * 16 * IN_F + k0 * 32);
      acc1[nf] = __builtin_amdgcn_mfma_f32_16x16x32_bf16(a, b, acc1[nf], 0, 0, 0);
    }
  }
#pragma unroll
  for (int nf = 0; nf < 8; nf++) {
    float bb = b1s[nf * 16 + lm];
#pragma unroll
    for (int q = 0; q < 4; q++) {
      int rr = (wv << 4) + (l >> 4) * 4 + q;
      h1s[rr][nf * 16 + lm] = tobf(fmaxf(acc1[nf][q] + bb, 0.f));
    }
  }
  __syncthreads();

  v4f acc2[3];
#pragma unroll
  for (int nf = 0; nf < 3; nf++) acc2[nf] = (v4f){0.f, 0.f, 0.f, 0.f};
#pragma unroll
  for (int k0 = 0; k0 < 4; k0++) {
    v8bf a = *(const v8bf*)&h1s[row][k0 * 32 + ko];
#pragma unroll
    for (int nf = 0; nf < 3; nf++) {
      v8bf b = *(const v8bf*)&w2s[nf * 16 + lm][k0 * 32 + ko];
      acc2[nf] = __builtin_amdgcn_mfma_f32_16x16x32_bf16(a, b, acc2[nf], 0, 0, 0);
    }
  }
#pragma unroll
  for (int nf = 0; nf < 3; nf++) {
    float bb = b2s[nf * 16 + lm];
#pragma unroll
    for (int q = 0; q < 4; q++) {
      int node = n0 + (wv << 4) + (l >> 4) * 4 + q;
      if (node < N_NODES)
        h0[(size_t)node * PAD_F + nf * 16 + lm] = tobf(acc2[nf][q] + bb);
    }
  }
  for (int i = tid; i < BM * 16; i += 256) {
    int r = i >> 4, c = 48 + (i & 15);
    int node = n0 + r;
    if (node < N_NODES) h0[(size_t)node * PAD_F + c] = (__bf16)0.f;
  }
}

// ---------------- CSR build: pass 1 — bucket by row>>9 ----------------------
// bcur is padded: counter for bucket b lives at bcur[b*16] (one per 64B line)
__global__ __launch_bounds__(256) void bucket_kernel(
    const int* __restrict__ rows, const int* __restrict__ cols,
    const float* __restrict__ vals, int* __restrict__ bcur,
    u64* __restrict__ brec, unsigned short* __restrict__ brow) {
  int e = blockIdx.x * 256 + threadIdx.x;
  if (e >= N_EDGES) return;
  int r = rows[e];
  int b = r >> 9;
  float v = vals[e] * (DROP_SCALE * (1.0f - ALPHA));
  u64 rec = ((u64)__float_as_uint(v) << 32) | (unsigned)cols[e];
  int p = atomicAdd(&bcur[b * 16], 1);
  size_t idx = (size_t)b * BCAP + p;
  brec[idx] = rec;
  brow[idx] = (unsigned short)(r & 511);
}

// ---------------- CSR build: bucket-count exclusive scan --------------------
__global__ __launch_bounds__(256) void bscan_kernel(const int* __restrict__ bcur,
                                                    int* __restrict__ bstart,
                                                    int* __restrict__ rowptr) {
  __shared__ int s[256];
  int t = threadIdx.x;
  int v = (t < NBUCK) ? bcur[t * 16] : 0;
  s[t] = v;
  __syncthreads();
  for (int off = 1; off < 256; off <<= 1) {
    int add = (t >= off) ? s[t - off] : 0;
    __syncthreads();
    s[t] += add;
    __syncthreads();
  }
  if (t < NBUCK) bstart[t] = s[t] - v;
  if (t == 0) rowptr[N_NODES] = N_EDGES;
}

// ---------------- CSR build: pass 2 — per-bucket LDS counting sort ----------
__global__ __launch_bounds__(512) void csr_kernel(
    const int* __restrict__ bcur, const int* __restrict__ bstart,
    const u64* __restrict__ brec, const unsigned short* __restrict__ brow,
    int* __restrict__ rowptr, u64* __restrict__ edges) {
  __shared__ int cnt[512];
  __shared__ int sc[512];
  const int b = blockIdx.x;
  const int t = threadIdx.x;
  const int n = bcur[b * 16];
  const int base = bstart[b];
  const size_t boff = (size_t)b * BCAP;

  cnt[t] = 0;
  __syncthreads();
  for (int i = t; i < n; i += 512) atomicAdd(&cnt[brow[boff + i]], 1);
  __syncthreads();

  int v = cnt[t];
  sc[t] = v;
  __syncthreads();
  for (int off = 1; off < 512; off <<= 1) {
    int add = (t >= off) ? sc[t - off] : 0;
    __syncthreads();
    sc[t] += add;
    __syncthreads();
  }
  int excl = sc[t] - v;
  int grow = b * 512 + t;
  if (grow < N_NODES) rowptr[grow] = base + excl;
  cnt[t] = excl;  // reuse as in-bucket cursor
  __syncthreads();

  for (int i = t; i < n; i += 512) {
    int rr = brow[boff + i];
    int p = atomicAdd(&cnt[rr], 1);
    edges[base + p] = brec[boff + i];
  }
}

// ---------------- propagation: wave/row, 8 edges x 8 lanes (dwordx4) -------
template <int FINAL>
__global__ __launch_bounds__(256) void prop_kernel(
    const __bf16* __restrict__ hin, __bf16* __restrict__ hout,
    float* __restrict__ fout, const int* __restrict__ rowptr,
    const u64* __restrict__ edges) {
  int wid = (blockIdx.x * 256 + threadIdx.x) >> 6;
  int lane = threadIdx.x & 63;
  if (wid >= N_NODES) return;
  const int g = lane >> 3;  // edge slot within wave
  const int t = lane & 7;   // feature octet: features 8t..8t+7
  int s = __builtin_amdgcn_readfirstlane(rowptr[wid]);
  int e = __builtin_amdgcn_readfirstlane(rowptr[wid + 1]);

  float acc[8];
#pragma unroll
  for (int j = 0; j < 8; j++) acc[j] = 0.f;

  if (g == 0) {  // self term, counted once
    uint4 q = *(const uint4*)(hin + (size_t)wid * PAD_F + t * 8);
    unsigned uu[4] = {q.x, q.y, q.z, q.w};
#pragma unroll
    for (int k = 0; k < 4; k++) {
      acc[2 * k] = ALPHA * __uint_as_float(uu[k] << 16);
      acc[2 * k + 1] = ALPHA * __uint_as_float(uu[k] & 0xffff0000u);
    }
  }

  int i = s + g;
  for (; i + 8 < e; i += 16) {
    u64 r0 = edges[i];
    u64 r1 = edges[i + 8];
    int c0 = (int)(r0 & 0xffffffffu);
    int c1 = (int)(r1 & 0xffffffffu);
    float v0 = __uint_as_float((unsigned)(r0 >> 32));
    float v1 = __uint_as_float((unsigned)(r1 >> 32));
    uint4 q0 = *(const uint4*)(hin + (size_t)c0 * PAD_F + t * 8);
    uint4 q1 = *(const uint4*)(hin + (size_t)c1 * PAD_F + t * 8);
    unsigned a0[4] = {q0.x, q0.y, q0.z, q0.w};
    unsigned a1[4] = {q1.x, q1.y, q1.z, q1.w};
#pragma unroll
    for (int k = 0; k < 4; k++) {
      acc[2 * k] = fmaf(v0, __uint_as_float(a0[k] << 16), acc[2 * k]);
      acc[2 * k + 1] = fmaf(v0, __uint_as_float(a0[k] & 0xffff0000u), acc[2 * k + 1]);
    }
#pragma unroll
    for (int k = 0; k < 4; k++) {
      acc[2 * k] = fmaf(v1, __uint_as_float(a1[k] << 16), acc[2 * k]);
      acc[2 * k + 1] = fmaf(v1, __uint_as_float(a1[k] & 0xffff0000u), acc[2 * k + 1]);
    }
  }
  if (i < e) {
    u64 r0 = edges[i];
    int c0 = (int)(r0 & 0xffffffffu);
    float v0 = __uint_as_float((unsigned)(r0 >> 32));
    uint4 q0 = *(const uint4*)(hin + (size_t)c0 * PAD_F + t * 8);
    unsigned a0[4] = {q0.x, q0.y, q0.z, q0.w};
#pragma unroll
    for (int k = 0; k < 4; k++) {
      acc[2 * k] = fmaf(v0, __uint_as_float(a0[k] << 16), acc[2 * k]);
      acc[2 * k + 1] = fmaf(v0, __uint_as_float(a0[k] & 0xffff0000u), acc[2 * k + 1]);
    }
  }

  // reduce the 8 edge-slot partials
#pragma unroll
  for (int m = 8; m <= 32; m <<= 1) {
#pragma unroll
    for (int j = 0; j < 8; j++) acc[j] += __shfl_xor(acc[j], m, 64);
  }

  if (g == 0) {
    if (FINAL) {
      if (t < 6) {
        float* dst = fout + (size_t)wid * OUT_F + t * 8;
        *(float4*)dst = make_float4(acc[0], acc[1], acc[2], acc[3]);
        *(float4*)(dst + 4) = make_float4(acc[4], acc[5], acc[6], acc[7]);
      }
    } else {
      unsigned w[4];
#pragma unroll
      for (int k = 0; k < 4; k++) {
        unsigned short lo = __builtin_bit_cast(unsigned short, (__bf16)acc[2 * k]);
        unsigned short hi = __builtin_bit_cast(unsigned short, (__bf16)acc[2 * k + 1]);
        w[k] = ((unsigned)hi << 16) | lo;
      }
      *(uint4*)(hout + (size_t)wid * PAD_F + t * 8) =
          make_uint4(w[0], w[1], w[2], w[3]);
    }
  }
}

// ---------------- launch ----------------------------------------------------
extern "C" void kernel_launch(void* const* d_in, const int* in_sizes, int n_in,
                              void* d_out, int out_size, void* d_ws,
                              size_t ws_size, hipStream_t stream) {
  const float* x = (const float*)d_in[0];
  const int* rows = (const int*)d_in[1];
  const int* cols = (const int*)d_in[2];
  const float* vals = (const float*)d_in[3];
  const float* W1 = (const float*)d_in[4];
  const float* b1 = (const float*)d_in[5];
  const float* W2 = (const float*)d_in[6];
  const float* b2 = (const float*)d_in[7];
  float* out = (float*)d_out;

  char* ws = (char*)d_ws;
  const size_t HA_OFF = 0;                  // 12,800,000
  const size_t HB_OFF = 12800000;           // 12,800,000
  const size_t EDGES_OFF = 25600000;        // 12,800,000
  const size_t BREC_OFF = 38400000;         // 196*10240*8 = 16,056,320
  const size_t BROW_OFF = 54456320;         // 196*10240*2 =  4,014,080
  const size_t ROWPTR_OFF = 58470400;       // 400,128
  const size_t BCUR_OFF = 58870528;         // 196*64 = 12,544
  const size_t BSTART_OFF = 58883072;       // 1,024
  const size_t W1T_OFF = 58884096;          // 65,536
  const size_t W2T_OFF = 58949632;          // 12,288  -> end 58,961,920

  __bf16* hA = (__bf16*)(ws + HA_OFF);
  __bf16* hB = (__bf16*)(ws + HB_OFF);
  u64* edges = (u64*)(ws + EDGES_OFF);
  u64* brec = (u64*)(ws + BREC_OFF);
  unsigned short* brow = (unsigned short*)(ws + BROW_OFF);
  int* rowptr = (int*)(ws + ROWPTR_OFF);
  int* bcur = (int*)(ws + BCUR_OFF);
  int* bstart = (int*)(ws + BSTART_OFF);
  __bf16* w1t = (__bf16*)(ws + W1T_OFF);
  __bf16* w2t = (__bf16*)(ws + W2T_OFF);

  conv_w<<<(HID * IN_F + OUT_F * HID + 255) / 256, 256, 0, stream>>>(W1, W2,
                                                                     w1t, w2t);
  mlp_mfma<<<(N_NODES + BM - 1) / BM, 256, 0, stream>>>(x, w1t, b1, w2t, b2, hA);

  hipMemsetAsync(bcur, 0, NBUCK * 64, stream);
  bucket_kernel<<<(N_EDGES + 255) / 256, 256, 0, stream>>>(rows, cols, vals,
                                                           bcur, brec, brow);
  bscan_kernel<<<1, 256, 0, stream>>>(bcur, bstart, rowptr);
  csr_kernel<<<NBUCK, 512, 0, stream>>>(bcur, bstart, brec, brow, rowptr, edges);

  const int PROP_BLOCKS = (N_NODES * 64 + 255) / 256;
  for (int k = 0; k < K_STEPS - 1; k++) {
    const __bf16* hin = (k & 1) ? hB : hA;
    __bf16* hout = (k & 1) ? hA : hB;
    prop_kernel<0><<<PROP_BLOCKS, 256, 0, stream>>>(hin, hout, nullptr, rowptr,
                                                    edges);
  }
  prop_kernel<1><<<PROP_BLOCKS, 256, 0, stream>>>(hB, nullptr, out, rowptr,
                                                  edges);
}

// Round 5
// 544.574 us; speedup vs baseline: 2.6479x; 1.2660x over previous
//
#include <hip/hip_runtime.h>

#define N_NODES 100000
#define N_EDGES 1600000
#define IN_F 256
#define HID 128
#define OUT_F 48
#define PAD_F 64
#define ALPHA 0.01f
#define K_STEPS 10
#define DROP_SCALE (1.0f / (1.0f + 1e-5f))

#define NBUCK 196      // buckets of 512 rows
#define BCAP 10240     // bucket capacity (mean 8163, 23 sigma headroom)
#define EPB 4096       // edges per bucketing block
#define ROW_MASK_CLR 0xFFFFFFFFFC01FFFFULL  // clears bits 25:17 (local row)

typedef __bf16 v8bf __attribute__((ext_vector_type(8)));
typedef float v4f __attribute__((ext_vector_type(4)));
typedef unsigned long long u64;

static __device__ __forceinline__ __bf16 tobf(float f) { return (__bf16)f; }

// ---------------- weight transpose+convert ---------------------------------
__global__ __launch_bounds__(256) void conv_w(const float* __restrict__ W1,
                                              const float* __restrict__ W2,
                                              __bf16* __restrict__ w1t,
                                              __bf16* __restrict__ w2t) {
  int i = blockIdx.x * 256 + threadIdx.x;
  if (i < HID * IN_F) {
    int n = i >> 8, k = i & 255;
    w1t[i] = tobf(W1[k * HID + n]);
  }
  int j = i - HID * IN_F;
  if (j >= 0 && j < OUT_F * HID) {
    int n = j >> 7, k = j & 127;
    w2t[j] = tobf(W2[k * OUT_F + n]);
  }
}

// ---------------- fused MLP via MFMA -> h0 bf16 [N][64] (cols 48-63 = 0) ---
#define BM 64
__global__ __launch_bounds__(256) void mlp_mfma(
    const float* __restrict__ x, const __bf16* __restrict__ w1t,
    const float* __restrict__ b1, const __bf16* __restrict__ w2t,
    const float* __restrict__ b2, __bf16* __restrict__ h0) {
  __shared__ __bf16 xs[BM][264];
  __shared__ __bf16 h1s[BM][136];
  __shared__ __bf16 w2s[OUT_F][136];
  __shared__ float b1s[HID];
  __shared__ float b2s[OUT_F];

  const int tid = threadIdx.x;
  const int n0 = blockIdx.x * BM;

  for (int i = tid; i < BM * 64; i += 256) {
    int r = i >> 6, c4 = i & 63;
    int gr = n0 + r;
    float4 v = make_float4(0.f, 0.f, 0.f, 0.f);
    if (gr < N_NODES) v = ((const float4*)(x + (size_t)gr * IN_F))[c4];
    __bf16* d = &xs[r][c4 * 4];
    d[0] = tobf(v.x); d[1] = tobf(v.y); d[2] = tobf(v.z); d[3] = tobf(v.w);
  }
  for (int i = tid; i < OUT_F * HID; i += 256) w2s[i >> 7][i & 127] = w2t[i];
  if (tid < HID) b1s[tid] = b1[tid];
  if (tid < OUT_F) b2s[tid] = b2[tid];
  __syncthreads();

  const int wv = tid >> 6;
  const int l = tid & 63;
  const int lm = l & 15;
  const int ko = (l >> 4) * 8;
  const int row = (wv << 4) + lm;

  v4f acc1[8];
#pragma unroll
  for (int nf = 0; nf < 8; nf++) acc1[nf] = (v4f){0.f, 0.f, 0.f, 0.f};

  const __bf16* w1base = w1t + (size_t)lm * IN_F + ko;
#pragma unroll
  for (int k0 = 0; k0 < 8; k0++) {
    v8bf a = *(const v8bf*)&xs[row][k0 * 32 + ko];
#pragma unroll
    for (int nf = 0; nf < 8; nf++) {
      v8bf b = *(const v8bf*)(w1base + nf * 16 * IN_F + k0 * 32);
      acc1[nf] = __builtin_amdgcn_mfma_f32_16x16x32_bf16(a, b, acc1[nf], 0, 0, 0);
    }
  }
#pragma unroll
  for (int nf = 0; nf < 8; nf++) {
    float bb = b1s[nf * 16 + lm];
#pragma unroll
    for (int q = 0; q < 4; q++) {
      int rr = (wv << 4) + (l >> 4) * 4 + q;
      h1s[rr][nf * 16 + lm] = tobf(fmaxf(acc1[nf][q] + bb, 0.f));
    }
  }
  __syncthreads();

  v4f acc2[3];
#pragma unroll
  for (int nf = 0; nf < 3; nf++) acc2[nf] = (v4f){0.f, 0.f, 0.f, 0.f};
#pragma unroll
  for (int k0 = 0; k0 < 4; k0++) {
    v8bf a = *(const v8bf*)&h1s[row][k0 * 32 + ko];
#pragma unroll
    for (int nf = 0; nf < 3; nf++) {
      v8bf b = *(const v8bf*)&w2s[nf * 16 + lm][k0 * 32 + ko];
      acc2[nf] = __builtin_amdgcn_mfma_f32_16x16x32_bf16(a, b, acc2[nf], 0, 0, 0);
    }
  }
#pragma unroll
  for (int nf = 0; nf < 3; nf++) {
    float bb = b2s[nf * 16 + lm];
#pragma unroll
    for (int q = 0; q < 4; q++) {
      int node = n0 + (wv << 4) + (l >> 4) * 4 + q;
      if (node < N_NODES)
        h0[(size_t)node * PAD_F + nf * 16 + lm] = tobf(acc2[nf][q] + bb);
    }
  }
  for (int i = tid; i < BM * 16; i += 256) {
    int r = i >> 4, c = 48 + (i & 15);
    int node = n0 + r;
    if (node < N_NODES) h0[(size_t)node * PAD_F + c] = (__bf16)0.f;
  }
}

// ---------------- CSR build pass 1: block-aggregated bucket binning ---------
// rec u64: val[63:32] | localrow[25:17] | col[16:0]
__global__ __launch_bounds__(256) void bucket_kernel(
    const int* __restrict__ rows, const int* __restrict__ cols,
    const float* __restrict__ vals, int* __restrict__ bcur,
    u64* __restrict__ brec) {
  __shared__ int lhist[NBUCK];
  __shared__ int lbase[NBUCK];
  const int t = threadIdx.x;
  const int base = blockIdx.x * EPB;

  for (int i = t; i < NBUCK; i += 256) lhist[i] = 0;
  __syncthreads();

  u64 rec[16];
  short bb[16];
  short pp[16];
#pragma unroll
  for (int j = 0; j < 4; j++) {
    int e = base + j * 1024 + t * 4;  // N_EDGES % 4 == 0, so e<N guards all 4
    bool ok = e < N_EDGES;
    int4 r4 = ok ? *(const int4*)(rows + e) : make_int4(0, 0, 0, 0);
    int4 c4 = ok ? *(const int4*)(cols + e) : make_int4(0, 0, 0, 0);
    float4 v4 = ok ? *(const float4*)(vals + e) : make_float4(0, 0, 0, 0);
    int rr[4] = {r4.x, r4.y, r4.z, r4.w};
    int cc[4] = {c4.x, c4.y, c4.z, c4.w};
    float vv[4] = {v4.x, v4.y, v4.z, v4.w};
#pragma unroll
    for (int q = 0; q < 4; q++) {
      int idx = j * 4 + q;
      int b = rr[q] >> 9;
      float v = vv[q] * (DROP_SCALE * (1.0f - ALPHA));
      rec[idx] = ((u64)__float_as_uint(v) << 32) |
                 ((u64)(rr[q] & 511) << 17) | (unsigned)cc[q];
      bb[idx] = ok ? (short)b : (short)-1;
      pp[idx] = ok ? (short)atomicAdd(&lhist[b], 1) : (short)0;
    }
  }
  __syncthreads();

  // one global window grab per bucket present in this block
  for (int i = t; i < NBUCK; i += 256) {
    int n = lhist[i];
    lbase[i] = (n > 0) ? atomicAdd(&bcur[i * 16], n) : 0;
  }
  __syncthreads();

#pragma unroll
  for (int j = 0; j < 16; j++) {
    if (bb[j] >= 0)
      brec[(size_t)bb[j] * BCAP + lbase[bb[j]] + pp[j]] = rec[j];
  }
}

// ---------------- CSR build: bucket-count exclusive scan --------------------
__global__ __launch_bounds__(256) void bscan_kernel(const int* __restrict__ bcur,
                                                    int* __restrict__ bstart,
                                                    int* __restrict__ rowptr) {
  __shared__ int s[256];
  int t = threadIdx.x;
  int v = (t < NBUCK) ? bcur[t * 16] : 0;
  s[t] = v;
  __syncthreads();
  for (int off = 1; off < 256; off <<= 1) {
    int add = (t >= off) ? s[t - off] : 0;
    __syncthreads();
    s[t] += add;
    __syncthreads();
  }
  if (t < NBUCK) bstart[t] = s[t] - v;
  if (t == 0) rowptr[N_NODES] = N_EDGES;
}

// ---------------- CSR build pass 2: per-bucket LDS counting sort ------------
__global__ __launch_bounds__(512) void csr_kernel(
    const int* __restrict__ bcur, const int* __restrict__ bstart,
    const u64* __restrict__ brec, int* __restrict__ rowptr,
    u64* __restrict__ edges) {
  __shared__ int cnt[512];
  __shared__ int sc[512];
  const int b = blockIdx.x;
  const int t = threadIdx.x;
  const int n = bcur[b * 16];
  const int base = bstart[b];
  const size_t boff = (size_t)b * BCAP;

  cnt[t] = 0;
  __syncthreads();
  for (int i = t; i < n; i += 512)
    atomicAdd(&cnt[(int)((brec[boff + i] >> 17) & 511)], 1);
  __syncthreads();

  int v = cnt[t];
  sc[t] = v;
  __syncthreads();
  for (int off = 1; off < 512; off <<= 1) {
    int add = (t >= off) ? sc[t - off] : 0;
    __syncthreads();
    sc[t] += add;
    __syncthreads();
  }
  int excl = sc[t] - v;
  int grow = b * 512 + t;
  if (grow < N_NODES) rowptr[grow] = base + excl;
  cnt[t] = excl;
  __syncthreads();

  for (int i = t; i < n; i += 512) {
    u64 rec = brec[boff + i];
    int rr = (int)((rec >> 17) & 511);
    int p = atomicAdd(&cnt[rr], 1);
    edges[base + p] = rec & ROW_MASK_CLR;
  }
}

// ---------------- propagation: wave/row, 8 edges x 8 lanes (dwordx4) -------
template <int FINAL>
__global__ __launch_bounds__(256) void prop_kernel(
    const __bf16* __restrict__ hin, __bf16* __restrict__ hout,
    float* __restrict__ fout, const int* __restrict__ rowptr,
    const u64* __restrict__ edges) {
  int wid = (blockIdx.x * 256 + threadIdx.x) >> 6;
  int lane = threadIdx.x & 63;
  if (wid >= N_NODES) return;
  const int g = lane >> 3;
  const int t = lane & 7;
  int s = __builtin_amdgcn_readfirstlane(rowptr[wid]);
  int e = __builtin_amdgcn_readfirstlane(rowptr[wid + 1]);

  float acc[8];
#pragma unroll
  for (int j = 0; j < 8; j++) acc[j] = 0.f;

  if (g == 0) {
    uint4 q = *(const uint4*)(hin + (size_t)wid * PAD_F + t * 8);
    unsigned uu[4] = {q.x, q.y, q.z, q.w};
#pragma unroll
    for (int k = 0; k < 4; k++) {
      acc[2 * k] = ALPHA * __uint_as_float(uu[k] << 16);
      acc[2 * k + 1] = ALPHA * __uint_as_float(uu[k] & 0xffff0000u);
    }
  }

  int i = s + g;
  for (; i + 8 < e; i += 16) {
    u64 r0 = edges[i];
    u64 r1 = edges[i + 8];
    int c0 = (int)(r0 & 0xffffffffu);
    int c1 = (int)(r1 & 0xffffffffu);
    float v0 = __uint_as_float((unsigned)(r0 >> 32));
    float v1 = __uint_as_float((unsigned)(r1 >> 32));
    uint4 q0 = *(const uint4*)(hin + (size_t)c0 * PAD_F + t * 8);
    uint4 q1 = *(const uint4*)(hin + (size_t)c1 * PAD_F + t * 8);
    unsigned a0[4] = {q0.x, q0.y, q0.z, q0.w};
    unsigned a1[4] = {q1.x, q1.y, q1.z, q1.w};
#pragma unroll
    for (int k = 0; k < 4; k++) {
      acc[2 * k] = fmaf(v0, __uint_as_float(a0[k] << 16), acc[2 * k]);
      acc[2 * k + 1] = fmaf(v0, __uint_as_float(a0[k] & 0xffff0000u), acc[2 * k + 1]);
    }
#pragma unroll
    for (int k = 0; k < 4; k++) {
      acc[2 * k] = fmaf(v1, __uint_as_float(a1[k] << 16), acc[2 * k]);
      acc[2 * k + 1] = fmaf(v1, __uint_as_float(a1[k] & 0xffff0000u), acc[2 * k + 1]);
    }
  }
  if (i < e) {
    u64 r0 = edges[i];
    int c0 = (int)(r0 & 0xffffffffu);
    float v0 = __uint_as_float((unsigned)(r0 >> 32));
    uint4 q0 = *(const uint4*)(hin + (size_t)c0 * PAD_F + t * 8);
    unsigned a0[4] = {q0.x, q0.y, q0.z, q0.w};
#pragma unroll
    for (int k = 0; k < 4; k++) {
      acc[2 * k] = fmaf(v0, __uint_as_float(a0[k] << 16), acc[2 * k]);
      acc[2 * k + 1] = fmaf(v0, __uint_as_float(a0[k] & 0xffff0000u), acc[2 * k + 1]);
    }
  }

#pragma unroll
  for (int m = 8; m <= 32; m <<= 1) {
#pragma unroll
    for (int j = 0; j < 8; j++) acc[j] += __shfl_xor(acc[j], m, 64);
  }

  if (g == 0) {
    if (FINAL) {
      if (t < 6) {
        float* dst = fout + (size_t)wid * OUT_F + t * 8;
        *(float4*)dst = make_float4(acc[0], acc[1], acc[2], acc[3]);
        *(float4*)(dst + 4) = make_float4(acc[4], acc[5], acc[6], acc[7]);
      }
    } else {
      unsigned w[4];
#pragma unroll
      for (int k = 0; k < 4; k++) {
        unsigned short lo = __builtin_bit_cast(unsigned short, (__bf16)acc[2 * k]);
        unsigned short hi = __builtin_bit_cast(unsigned short, (__bf16)acc[2 * k + 1]);
        w[k] = ((unsigned)hi << 16) | lo;
      }
      *(uint4*)(hout + (size_t)wid * PAD_F + t * 8) =
          make_uint4(w[0], w[1], w[2], w[3]);
    }
  }
}

// ---------------- launch ----------------------------------------------------
extern "C" void kernel_launch(void* const* d_in, const int* in_sizes, int n_in,
                              void* d_out, int out_size, void* d_ws,
                              size_t ws_size, hipStream_t stream) {
  const float* x = (const float*)d_in[0];
  const int* rows = (const int*)d_in[1];
  const int* cols = (const int*)d_in[2];
  const float* vals = (const float*)d_in[3];
  const float* W1 = (const float*)d_in[4];
  const float* b1 = (const float*)d_in[5];
  const float* W2 = (const float*)d_in[6];
  const float* b2 = (const float*)d_in[7];
  float* out = (float*)d_out;

  char* ws = (char*)d_ws;
  const size_t HA_OFF = 0;                  // 12,800,000
  const size_t HB_OFF = 12800000;           // 12,800,000
  const size_t EDGES_OFF = 25600000;        // 12,800,000
  const size_t BREC_OFF = 38400000;         // 196*10240*8 = 16,056,320
  const size_t ROWPTR_OFF = 54456320;       // 400,128
  const size_t BCUR_OFF = 54856448;         // 196*64 = 12,544
  const size_t BSTART_OFF = 54868992;       // 1,024
  const size_t W1T_OFF = 54870016;          // 65,536
  const size_t W2T_OFF = 54935552;          // 12,288

  __bf16* hA = (__bf16*)(ws + HA_OFF);
  __bf16* hB = (__bf16*)(ws + HB_OFF);
  u64* edges = (u64*)(ws + EDGES_OFF);
  u64* brec = (u64*)(ws + BREC_OFF);
  int* rowptr = (int*)(ws + ROWPTR_OFF);
  int* bcur = (int*)(ws + BCUR_OFF);
  int* bstart = (int*)(ws + BSTART_OFF);
  __bf16* w1t = (__bf16*)(ws + W1T_OFF);
  __bf16* w2t = (__bf16*)(ws + W2T_OFF);

  conv_w<<<(HID * IN_F + OUT_F * HID + 255) / 256, 256, 0, stream>>>(W1, W2,
                                                                     w1t, w2t);
  mlp_mfma<<<(N_NODES + BM - 1) / BM, 256, 0, stream>>>(x, w1t, b1, w2t, b2, hA);

  hipMemsetAsync(bcur, 0, NBUCK * 64, stream);
  bucket_kernel<<<(N_EDGES + EPB - 1) / EPB, 256, 0, stream>>>(rows, cols, vals,
                                                               bcur, brec);
  bscan_kernel<<<1, 256, 0, stream>>>(bcur, bstart, rowptr);
  csr_kernel<<<NBUCK, 512, 0, stream>>>(bcur, bstart, brec, rowptr, edges);

  const int PROP_BLOCKS = (N_NODES * 64 + 255) / 256;
  for (int k = 0; k < K_STEPS - 1; k++) {
    const __bf16* hin = (k & 1) ? hB : hA;
    __bf16* hout = (k & 1) ? hA : hB;
    prop_kernel<0><<<PROP_BLOCKS, 256, 0, stream>>>(hin, hout, nullptr, rowptr,
                                                    edges);
  }
  prop_kernel<1><<<PROP_BLOCKS, 256, 0, stream>>>(hB, nullptr, out, rowptr,
                                                  edges);
}